// Round 10
// baseline (1446.933 us; speedup 1.0000x reference)
//
#include <hip/hip_runtime.h>

#define NN 4096
#define SB 128             // sub-block / publish granularity
#define NSB 32             // sub-blocks total
#define NWG 8              // owner WGs
#define SPW 4              // sub-blocks per WG
#define ROWS 512           // rows per WG
#define MAXT 8
#define MAXE (MAXT * NSB)  // 256 mailbox stages max
#define NTH 1024           // 16 waves: wave 0 = solver/poller, 1-15 = workers
#define MASK63 0x7FFFFFFFFFFFFFFFull
#define MASK62 0x3FFFFFFFFFFFFFFFull
#define TOPBIT 0x8000000000000000ull

// ---------------------------------------------------------------------------
// Kernel 1: zero mailboxes + parallel partial matvec  a_partial = W @ x
// (unchanged from passing rounds)
// ---------------------------------------------------------------------------
__global__ __launch_bounds__(256)
void hop_init(const float* __restrict__ x, const float* __restrict__ W,
              unsigned long long* __restrict__ slots, float* __restrict__ partial_buf)
{
    const int tid = threadIdx.x, bid = blockIdx.x;
    const int lane = tid & 63, w = tid >> 6;
    const int lam = lane & 31, half = lane >> 5;

    if (bid == 0) {
        for (int i = tid; i < MAXE * 8; i += 256) slots[i] = 0ull;
    }

    const int tm = bid >> 3, tc = bid & 7;
    const int rbase = tm * SB, cbase = tc * 512;

    float4 xv[4];
#pragma unroll
    for (int u = 0; u < 4; ++u)
        xv[u] = *(const float4*)(x + cbase + 4 * lam + 128 * u);

#pragma unroll 2
    for (int it = 0; it < 16; ++it) {
        const int r = w * 32 + it * 2 + half;
        const float* wrow = W + (size_t)(rbase + r) * NN + cbase;
        float p = 0.f;
#pragma unroll
        for (int u = 0; u < 4; ++u) {
            float4 wv = *(const float4*)(wrow + 4 * lam + 128 * u);
            p = fmaf(wv.x, xv[u].x, p); p = fmaf(wv.y, xv[u].y, p);
            p = fmaf(wv.z, xv[u].z, p); p = fmaf(wv.w, xv[u].w, p);
        }
#pragma unroll
        for (int s = 16; s; s >>= 1) p += __shfl_xor(p, s);
        if (lam == 0) partial_buf[(size_t)bid * SB + r] = p;
    }
}

// Apply a 128-col delta (in dl_p) to local rows [r0,r1) of a_lds, streaming W.
// Executed by worker waves 1..15; row pairs strided across waves.
__device__ __forceinline__ void apply_rows(
    const float* __restrict__ W, int rowbase, float* a_lds,
    const float* dl_p, int cb, int r0, int r1, int wv, int lam, int half)
{
    const float4 d4 = *(const float4*)(dl_p + 4 * lam);
    const int npairs = (r1 - r0) >> 1;
    for (int i = wv - 1; i < npairs; i += 15) {
        const int r = r0 + 2 * i + half;
        const float* wr = W + (size_t)(rowbase + r) * NN + cb + 4 * lam;
        const float4 wvv = *(const float4*)wr;
        float p = fmaf(wvv.x, d4.x, fmaf(wvv.y, d4.y, fmaf(wvv.z, d4.z, wvv.w * d4.w)));
#pragma unroll
        for (int sh = 16; sh; sh >>= 1) p += __shfl_xor(p, sh);
        if (lam == 0) a_lds[r] += p;
    }
}

// ---------------------------------------------------------------------------
// Kernel 2: 8 owner WGs x 512 rows (4 sub-blocks of 128 each).
// 28/32 handoffs per sweep are LDS-local; only 4/32 cross WG mailboxes.
// Wave 0 = solver/poller; waves 1-15 = streaming appliers / stagers.
// ---------------------------------------------------------------------------
__global__ __launch_bounds__(NTH)
void hop_main(const float* __restrict__ x, const float* __restrict__ W,
              const int* __restrict__ maxit, float* __restrict__ out,
              unsigned long long* __restrict__ slots,
              const float* __restrict__ partial_buf)
{
    __shared__ float wdT[2][SB][SB + 1];        // double-buffered diag tile (transposed)
    __shared__ float x_lds[NN];                 // initial state (for sweep-0 deltas)
    __shared__ float a_lds[ROWS];               // my running activations
    __shared__ float sold_lds[ROWS];            // my current state
    __shared__ float dl[2][SB];                 // stage-parity delta buffers
    __shared__ unsigned long long pm[2][NSB][2];// sweep-parity masks of foreign subs
    __shared__ int pend_any[2];
    __shared__ int pend_cb[2];

    const int tid = threadIdx.x;
    const int m = blockIdx.x;
    const int lane = tid & 63, wv = tid >> 6;
    const int lam = lane & 31, half = lane >> 5;
    const int rowbase = m * ROWS;

    int T = *maxit; if (T > MAXT) T = MAXT; if (T < 0) T = 0;
    const long long tstart = clock64();

    for (int i = tid; i < NN; i += NTH) x_lds[i] = x[i];
    // stage wdT[0] = transposed diag tile of my sub 0
    for (int l = tid; l < SB * SB; l += NTH) {
        const int i = l >> 7, j = l & 127;
        wdT[0][j][i] = W[(size_t)(rowbase + i) * NN + rowbase + j];
    }
    if (tid < ROWS) {
        float s = 0.f;
#pragma unroll
        for (int c = 0; c < 8; ++c)
            s += partial_buf[(size_t)((m * SPW + (tid >> 7)) * 8 + c) * SB + (tid & 127)];
        a_lds[tid] = s;
        sold_lds[tid] = x[rowbase + tid];
    }
    if (tid < 2) { pend_any[tid] = 0; pend_cb[tid] = 0; }
    int cur = 0;
    __syncthreads();

    for (int t = 0; t < T * NSB; ++t) {
        const int b = t & (NSB - 1);
        const int s = t >> 5;
        const int pp = t & 1, qq = pp ^ 1;
        if ((b >> 2) != m) {
            // ================= foreign stage: 1 barrier =================
            if (wv == 0) {
                // poll the 3-qword self-validating mailbox
                const unsigned long long* sl = slots + (size_t)t * 8;
                const int d = (b < SPW * m) ? (SPW * m - b) : (NSB - b + SPW * m);
                unsigned long long q0, q1, q2;
                long long iters = 0;
                for (;;) {
                    q0 = __hip_atomic_load(&sl[0], __ATOMIC_RELAXED, __HIP_MEMORY_SCOPE_AGENT);
                    q1 = __hip_atomic_load(&sl[1], __ATOMIC_RELAXED, __HIP_MEMORY_SCOPE_AGENT);
                    q2 = __hip_atomic_load(&sl[2], __ATOMIC_RELAXED, __HIP_MEMORY_SCOPE_AGENT);
                    if ((q0 & q1 & q2) >> 63) break;
                    if (d == 1)      __builtin_amdgcn_s_sleep(1);
                    else if (d <= 4) __builtin_amdgcn_s_sleep(4);
                    else             __builtin_amdgcn_s_sleep(32);
                    if (((++iters) & 63) == 0 && (clock64() - tstart) > 500000000LL) break;
                }
                const unsigned long long mm0 = (q0 & MASK63) | (q1 << 63);
                const unsigned long long mm1 = ((q1 >> 1) & MASK62) | (q2 << 62);
                const unsigned long long p0 = pm[(s - 1) & 1][b][0];
                const unsigned long long p1 = pm[(s - 1) & 1][b][1];
                const int any = (s == 0) || (mm0 != p0) || (mm1 != p1);
                // build bit-exact delta for both halves (2 entries per lane)
                {
                    const int j0 = lane;
                    const float cur0 = ((mm0 >> j0) & 1) ? 1.f : -1.f;
                    const float prev0 = (s == 0) ? x_lds[b * SB + j0]
                                                 : (((p0 >> j0) & 1) ? 1.f : -1.f);
                    dl[pp][j0] = cur0 - prev0;
                    const float cur1 = ((mm1 >> j0) & 1) ? 1.f : -1.f;
                    const float prev1 = (s == 0) ? x_lds[b * SB + 64 + j0]
                                                 : (((p1 >> j0) & 1) ? 1.f : -1.f);
                    dl[pp][64 + j0] = cur1 - prev1;
                }
                if (lane == 0) {
                    pm[s & 1][b][0] = mm0;
                    pm[s & 1][b][1] = mm1;
                    pend_any[pp] = any;
                    pend_cb[pp] = b * SB;
                }
            } else {
                // workers: apply pending delta (t-1) to ALL my rows, overlapping the poll
                if (pend_any[qq])
                    apply_rows(W, rowbase, a_lds, dl[qq], pend_cb[qq], 0, ROWS, wv, lam, half);
            }
            __syncthreads();
        } else {
            // ================= my solve stage: 2 barriers =================
            const int lb = b & (SPW - 1);
            // quick phase: pending delta onto the rows my chain is about to read
            if (wv > 0 && pend_any[qq])
                apply_rows(W, rowbase, a_lds, dl[qq], pend_cb[qq],
                           lb * SB, lb * SB + SB, wv, lam, half);
            __syncthreads();
            if (wv == 0) {
                // ---- sequential 128-neuron chain (proven code) ----
                float (*wd)[SB + 1] = wdT[cur];
                float c0 = a_lds[lb * SB + lane], c1 = a_lds[lb * SB + 64 + lane];
                float sold0 = sold_lds[lb * SB + lane], sold1 = sold_lds[lb * SB + 64 + lane];
                const float dp0 = 1.f - sold0, dm0 = -1.f - sold0;
                const float dp1 = 1.f - sold1, dm1 = -1.f - sold1;
                const float cand0 = c0 > 0.f ? dp0 : dm0;
                const float cand1 = c1 > 0.f ? dp1 : dm1;
                const unsigned long long bz = __ballot((cand0 != 0.f) || (cand1 != 0.f));
                float vdf0 = 0.f, vdf1 = 0.f;
                const int zero_all = (bz == 0ULL);
                if (!zero_all) {
                    float vsn0 = sold0, vsn1 = sold1;
                    float pw0[6], pw1[6];
#pragma unroll
                    for (int u = 0; u < 6; ++u) { pw0[u] = wd[u][lane]; pw1[u] = wd[u][lane + 64]; }
#pragma unroll
                    for (int j = 0; j < 64; ++j) {
                        const float dq = c0 > 0.f ? dp0 : dm0;
                        const float sq = c0 > 0.f ? 1.f : -1.f;
                        const float bc = __int_as_float(
                            __builtin_amdgcn_readlane(__float_as_int(dq), j));
                        const bool me = (lane == j);
                        vdf0 = me ? dq : vdf0;
                        vsn0 = me ? sq : vsn0;
                        const float w0 = pw0[j % 6], w1 = pw1[j % 6];
                        pw0[j % 6] = wd[j + 6][lane];
                        pw1[j % 6] = wd[j + 6][lane + 64];
                        c0 = fmaf(w0, bc, c0);
                        c1 = fmaf(w1, bc, c1);
                    }
                    const float cnd1 = c1 > 0.f ? dp1 : dm1;
                    const unsigned long long bz1 = __ballot(cnd1 != 0.f);
                    if (bz1 != 0ULL) {
#pragma unroll
                        for (int j = 64; j < 128; ++j) {
                            const float dq = c1 > 0.f ? dp1 : dm1;
                            const float sq = c1 > 0.f ? 1.f : -1.f;
                            const float bc = __int_as_float(
                                __builtin_amdgcn_readlane(__float_as_int(dq), j & 63));
                            const bool me = (lane == (j & 63));
                            vdf1 = me ? dq : vdf1;
                            vsn1 = me ? sq : vsn1;
                            const float w1 = pw1[j % 6];
                            if (j + 6 < SB) pw1[j % 6] = wd[j + 6][lane + 64];
                            c1 = fmaf(w1, bc, c1);
                        }
                    }
                    sold0 = vsn0; sold1 = vsn1;
                    sold_lds[lb * SB + lane] = sold0;
                    sold_lds[lb * SB + 64 + lane] = sold1;
                }
                // publish 3-qword self-validating mask packet
                {
                    const unsigned long long b0 = __ballot(sold0 > 0.f);
                    const unsigned long long b1 = __ballot(sold1 > 0.f);
                    unsigned long long* sl = slots + (size_t)t * 8;
                    if (lane == 0) {
                        __hip_atomic_store(&sl[0], TOPBIT | (b0 & MASK63),
                                           __ATOMIC_RELAXED, __HIP_MEMORY_SCOPE_AGENT);
                        __hip_atomic_store(&sl[1], TOPBIT | (b0 >> 63) | ((b1 & MASK62) << 1),
                                           __ATOMIC_RELAXED, __HIP_MEMORY_SCOPE_AGENT);
                        __hip_atomic_store(&sl[2], TOPBIT | (b1 >> 62),
                                           __ATOMIC_RELAXED, __HIP_MEMORY_SCOPE_AGENT);
                    }
                }
                dl[pp][lane] = vdf0;
                dl[pp][lane + 64] = vdf1;
                if (lane == 0) { pend_any[pp] = !zero_all; pend_cb[pp] = b * SB; }
            } else {
                // workers: finish pending on remaining rows + stage next diag tile
                if (pend_any[qq]) {
                    apply_rows(W, rowbase, a_lds, dl[qq], pend_cb[qq],
                               0, lb * SB, wv, lam, half);
                    apply_rows(W, rowbase, a_lds, dl[qq], pend_cb[qq],
                               lb * SB + SB, ROWS, wv, lam, half);
                }
                const int nlb = (lb + 1) & (SPW - 1);
                const int nb = rowbase + nlb * SB;
                for (int l = tid - 64; l < SB * SB; l += (NTH - 64)) {
                    const int i = l >> 7, j = l & 127;
                    wdT[cur ^ 1][j][i] = W[(size_t)(nb + i) * NN + nb + j];
                }
            }
            __syncthreads();
            cur ^= 1;
        }
    }

    if (tid < ROWS) out[rowbase + tid] = sold_lds[tid];
}

// ---------------------------------------------------------------------------
extern "C" void kernel_launch(void* const* d_in, const int* in_sizes, int n_in,
                              void* d_out, int out_size, void* d_ws, size_t ws_size,
                              hipStream_t stream) {
    const float* x = (const float*)d_in[0];
    const float* W = (const float*)d_in[1];
    const int* maxit = (const int*)d_in[2];
    float* out = (float*)d_out;

    char* ws = (char*)d_ws;
    unsigned long long* slots = (unsigned long long*)ws;              // 16 KB
    float* partial_buf = (float*)(ws + (size_t)MAXE * 64);            // 128 KB
    if (ws_size < (size_t)(MAXE * 64 + 256 * SB * 4)) return;

    hipLaunchKernelGGL(hop_init, dim3(256), dim3(256), 0, stream,
                       x, W, slots, partial_buf);

    void* args[6];
    args[0] = (void*)&x; args[1] = (void*)&W; args[2] = (void*)&maxit;
    args[3] = (void*)&out; args[4] = (void*)&slots; args[5] = (void*)&partial_buf;
    (void)hipLaunchCooperativeKernel(hop_main, dim3(NWG), dim3(NTH), args, 0u, stream);
}

// Round 12
// 1165.430 us; speedup vs baseline: 1.2415x; 1.2415x over previous
//
#include <hip/hip_runtime.h>

#define NN 4096
#define BB 128
#define GG 32          // NN / BB
#define MAXT 8
#define MAXE (MAXT * GG)
#define NTH 320        // wave 0: poll/solve/publish; waves 1-4: apply + prefetch
#define MASK63 0x7FFFFFFFFFFFFFFFull
#define MASK62 0x3FFFFFFFFFFFFFFFull
#define TOPBIT 0x8000000000000000ull

typedef unsigned long long ull;
typedef unsigned long long ull2 __attribute__((ext_vector_type(2)));

// ---------------------------------------------------------------------------
// Kernel 1: zero mailboxes + parallel partial matvec  a_partial = W @ x
// ---------------------------------------------------------------------------
__global__ __launch_bounds__(256)
void hop_init(const float* __restrict__ x, const float* __restrict__ W,
              ull* __restrict__ slots, float* __restrict__ partial_buf)
{
    const int tid = threadIdx.x, bid = blockIdx.x;
    const int lane = tid & 63, w = tid >> 6;
    const int lam = lane & 31, half = lane >> 5;

    if (bid == 0) {
        for (int i = tid; i < MAXE * 8; i += 256) slots[i] = 0ull;
    }

    const int tm = bid >> 3, tc = bid & 7;
    const int rbase = tm * BB, cbase = tc * 512;

    float4 xv[4];
#pragma unroll
    for (int u = 0; u < 4; ++u)
        xv[u] = *(const float4*)(x + cbase + 4 * lam + 128 * u);

#pragma unroll 2
    for (int it = 0; it < 16; ++it) {
        const int r = w * 32 + it * 2 + half;
        const float* wrow = W + (size_t)(rbase + r) * NN + cbase;
        float p = 0.f;
#pragma unroll
        for (int u = 0; u < 4; ++u) {
            float4 wv = *(const float4*)(wrow + 4 * lam + 128 * u);
            p = fmaf(wv.x, xv[u].x, p); p = fmaf(wv.y, xv[u].y, p);
            p = fmaf(wv.z, xv[u].z, p); p = fmaf(wv.w, xv[u].w, p);
        }
#pragma unroll
        for (int s = 16; s; s >>= 1) p += __shfl_xor(p, s);
        if (lam == 0) partial_buf[(size_t)bid * BB + r] = p;
    }
}

// ---------------------------------------------------------------------------
// Kernel 2: 32 owner WGs, barrier-free dataflow pipeline.
// Wave 0: poll mailbox -> build delta -> (own stage: chain-solve + publish).
// Waves 1-4: apply delta to a_lds (own 32 rows each) + prefetch next W tile.
// All intra-WG sync via LDS acquire/release flags. No __syncthreads in loop.
// ---------------------------------------------------------------------------
__global__ __launch_bounds__(NTH)
void hop_main(const float* __restrict__ x, const float* __restrict__ W,
              const int* __restrict__ maxit, float* __restrict__ out,
              ull* __restrict__ slots, const float* __restrict__ partial_buf)
{
    __shared__ float wdT[BB][BB + 1];   // transposed diagonal tile (constant)
    __shared__ float x_lds[NN];         // initial state (sweep-0 prev values)
    __shared__ float a_lds[BB];         // my running activations
    __shared__ float d_lds[BB];         // current stage's delta vector
    __shared__ ull   pm[2][GG][2];      // per-sweep-parity published masks
    __shared__ int   delta_seq;         // last stage with delta ready
    __shared__ int   delta_any;
    __shared__ int   applied_seq[4];    // per-worker applied progress

    const int tid = threadIdx.x;
    const int m = blockIdx.x;
    const int lane = tid & 63, wv = tid >> 6;
    const int lam = lane & 31, half = lane >> 5;
    const int bm = m * BB;

    int T = *maxit; if (T > MAXT) T = MAXT; if (T < 0) T = 0;
    const int TT = T * GG;
    const long long tstart = clock64();

    // ---- init (one barrier total) ----
    for (int l = tid; l < BB * BB; l += NTH) {
        const int i = l >> 7, j = l & 127;
        wdT[j][i] = W[(size_t)(bm + i) * NN + bm + j];
    }
    for (int i = tid; i < NN; i += NTH) x_lds[i] = x[i];
    if (tid < BB) {
        float s = 0.f;
#pragma unroll
        for (int c = 0; c < 8; ++c) s += partial_buf[(size_t)(m * 8 + c) * BB + tid];
        a_lds[tid] = s;
    }
    if (tid == 0) { delta_seq = -1; delta_any = 0; }
    if (tid < 4) applied_seq[tid] = -1;
    float sold0 = 0.f, sold1 = 0.f;
    if (wv == 0) { sold0 = x[bm + lane]; sold1 = x[bm + 64 + lane]; }
    __syncthreads();

    if (wv == 0) {
        // =================== wave 0: poll / solve / publish ===================
        for (int t = 0; t < TT; ++t) {
            const int k = t & (GG - 1);
            const int s = t >> 5;
            // gate: workers caught up through t-1 (protects d_lds and a_lds)
            for (int w = 0; w < 4; ++w) {
                long long it2 = 0;
                while (__hip_atomic_load(&applied_seq[w], __ATOMIC_ACQUIRE,
                                         __HIP_MEMORY_SCOPE_WORKGROUP) < t - 1) {
                    if (((++it2) & 255) == 0 && (clock64() - tstart) > 500000000LL) break;
                }
            }
            if (k != m) {
                // ---- detect: acquire-spin on q2 only, then 16B plain load ----
                const ull* sl = slots + (size_t)t * 8;
                const int dist = (m - k + GG) & (GG - 1);
                ull q2;
                long long iters = 0;
                for (;;) {
                    q2 = __hip_atomic_load(&sl[2], __ATOMIC_ACQUIRE,
                                           __HIP_MEMORY_SCOPE_AGENT);
                    if (q2 >> 63) break;
                    if (dist == 1)      __builtin_amdgcn_s_sleep(1);
                    else if (dist <= 4) __builtin_amdgcn_s_sleep(4);
                    else                __builtin_amdgcn_s_sleep(32);
                    if (((++iters) & 63) == 0 && (clock64() - tstart) > 500000000LL) break;
                }
                const ull2 q01 = *(const ull2*)sl;      // ordered after acquire
                const ull q0 = q01.x, q1 = q01.y;
                const ull mm0 = (q0 & MASK63) | (q1 << 63);
                const ull mm1 = ((q1 >> 1) & MASK62) | (q2 << 62);
                const ull p0 = pm[(s - 1) & 1][k][0];
                const ull p1 = pm[(s - 1) & 1][k][1];
                const int any = (s == 0) || (mm0 != p0) || (mm1 != p1);
                // build bit-exact delta (2 entries per lane)
                {
                    const float c0 = ((mm0 >> lane) & 1) ? 1.f : -1.f;
                    const float pr0 = (s == 0) ? x_lds[k * BB + lane]
                                               : (((p0 >> lane) & 1) ? 1.f : -1.f);
                    d_lds[lane] = c0 - pr0;
                    const float c1 = ((mm1 >> lane) & 1) ? 1.f : -1.f;
                    const float pr1 = (s == 0) ? x_lds[k * BB + 64 + lane]
                                               : (((p1 >> lane) & 1) ? 1.f : -1.f);
                    d_lds[64 + lane] = c1 - pr1;
                }
                if (lane == 0) {
                    pm[s & 1][k][0] = mm0;
                    pm[s & 1][k][1] = mm1;
                    delta_any = any;
                    __hip_atomic_store(&delta_seq, t, __ATOMIC_RELEASE,
                                       __HIP_MEMORY_SCOPE_WORKGROUP);
                }
            } else {
                // ---- my solve: a_lds is current (gate above) ----
                float c0 = a_lds[lane], c1 = a_lds[lane + 64];
                const float dp0 = 1.f - sold0, dm0 = -1.f - sold0;
                const float dp1 = 1.f - sold1, dm1 = -1.f - sold1;
                const float cand0 = c0 > 0.f ? dp0 : dm0;
                const float cand1 = c1 > 0.f ? dp1 : dm1;
                const ull bz = __ballot((cand0 != 0.f) || (cand1 != 0.f));
                const int zero_all = (bz == 0ULL);
                if (!zero_all) {
                    float vsn0 = sold0, vsn1 = sold1;
                    float pw0[6], pw1[6];
#pragma unroll
                    for (int u = 0; u < 6; ++u) { pw0[u] = wdT[u][lane]; pw1[u] = wdT[u][lane + 64]; }
#pragma unroll
                    for (int j = 0; j < 64; ++j) {      // neurons 0..63
                        const float dq = c0 > 0.f ? dp0 : dm0;
                        const float sq = c0 > 0.f ? 1.f : -1.f;
                        const float bc = __int_as_float(
                            __builtin_amdgcn_readlane(__float_as_int(dq), j));
                        const bool me = (lane == j);
                        vsn0 = me ? sq : vsn0;
                        const float w0 = pw0[j % 6], w1 = pw1[j % 6];
                        pw0[j % 6] = wdT[j + 6][lane];
                        pw1[j % 6] = wdT[j + 6][lane + 64];
                        c0 = fmaf(w0, bc, c0);
                        c1 = fmaf(w1, bc, c1);
                    }
                    const float cnd1 = c1 > 0.f ? dp1 : dm1;
                    const ull bz1 = __ballot(cnd1 != 0.f);
                    if (bz1 != 0ULL) {
                        // pw0 now holds wdT[64..69][lane]; keep BOTH accumulators
                        // complete so the write-back to a_lds is the full
                        // 128-column intra-block correction (fix for R11 bug).
#pragma unroll
                        for (int j = 64; j < 128; ++j) {  // neurons 64..127
                            const float dq = c1 > 0.f ? dp1 : dm1;
                            const float sq = c1 > 0.f ? 1.f : -1.f;
                            const float bc = __int_as_float(
                                __builtin_amdgcn_readlane(__float_as_int(dq), j & 63));
                            const bool me = (lane == (j & 63));
                            vsn1 = me ? sq : vsn1;
                            const float w0 = pw0[j % 6], w1 = pw1[j % 6];
                            if (j + 6 < BB) {
                                pw0[j % 6] = wdT[j + 6][lane];
                                pw1[j % 6] = wdT[j + 6][lane + 64];
                            }
                            c0 = fmaf(w0, bc, c0);
                            c1 = fmaf(w1, bc, c1);
                        }
                    }
                    sold0 = vsn0; sold1 = vsn1;
                    a_lds[lane] = c0;               // full intra-block correction
                    a_lds[lane + 64] = c1;          // (both halves, all 128 cols)
                }
                // publish: q0,q1 relaxed; q2 RELEASE (orders q0,q1 before it)
                {
                    const ull b0 = __ballot(sold0 > 0.f);
                    const ull b1 = __ballot(sold1 > 0.f);
                    ull* sl = slots + (size_t)t * 8;
                    if (lane == 0) {
                        __hip_atomic_store(&sl[0], TOPBIT | (b0 & MASK63),
                                           __ATOMIC_RELAXED, __HIP_MEMORY_SCOPE_AGENT);
                        __hip_atomic_store(&sl[1], TOPBIT | (b0 >> 63) | ((b1 & MASK62) << 1),
                                           __ATOMIC_RELAXED, __HIP_MEMORY_SCOPE_AGENT);
                        __hip_atomic_store(&sl[2], TOPBIT | (b1 >> 62),
                                           __ATOMIC_RELEASE, __HIP_MEMORY_SCOPE_AGENT);
                        pm[s & 1][k][0] = b0;       // record own mask
                        pm[s & 1][k][1] = b1;
                        delta_any = 0;              // workers skip apply
                        __hip_atomic_store(&delta_seq, t, __ATOMIC_RELEASE,
                                           __HIP_MEMORY_SCOPE_WORKGROUP);
                    }
                }
            }
        }
        out[bm + lane] = sold0;
        out[bm + 64 + lane] = sold1;
    } else {
        // =================== waves 1-4: apply + prefetch ===================
        const int w = wv - 1;
        float4 wpre[16];
        // prologue: prefetch tile for stage 0 (column block 0)
#pragma unroll
        for (int it = 0; it < 16; ++it) {
            const int r = w * 32 + it * 2 + half;
            wpre[it] = *(const float4*)(W + (size_t)(bm + r) * NN + 0 * BB + 4 * lam);
        }
        for (int t = 0; t < TT; ++t) {
            // wait for this stage's delta verdict
            long long iters = 0;
            while (__hip_atomic_load(&delta_seq, __ATOMIC_ACQUIRE,
                                     __HIP_MEMORY_SCOPE_WORKGROUP) < t) {
                __builtin_amdgcn_s_sleep(1);
                if (((++iters) & 255) == 0 && (clock64() - tstart) > 500000000LL) break;
            }
            if (delta_any) {
                const float4 d4 = *(const float4*)&d_lds[4 * lam];
#pragma unroll
                for (int it = 0; it < 16; ++it) {
                    const int r = w * 32 + it * 2 + half;
                    const float4 wvv = wpre[it];
                    float p = fmaf(wvv.x, d4.x, fmaf(wvv.y, d4.y,
                              fmaf(wvv.z, d4.z, wvv.w * d4.w)));
#pragma unroll
                    for (int sh = 16; sh; sh >>= 1) p += __shfl_xor(p, sh);
                    if (lam == 0) a_lds[r] += p;    // fixed lane per row
                }
            }
            if (lane == 0)
                __hip_atomic_store(&applied_seq[w], t, __ATOMIC_RELEASE,
                                   __HIP_MEMORY_SCOPE_WORKGROUP);
            // prefetch next stage's tile (W only -- no flag dependency)
            if (t + 1 < TT) {
                const int kn = (t + 1) & (GG - 1);
#pragma unroll
                for (int it = 0; it < 16; ++it) {
                    const int r = w * 32 + it * 2 + half;
                    wpre[it] = *(const float4*)(W + (size_t)(bm + r) * NN + kn * BB + 4 * lam);
                }
            }
        }
    }
}

// ---------------------------------------------------------------------------
extern "C" void kernel_launch(void* const* d_in, const int* in_sizes, int n_in,
                              void* d_out, int out_size, void* d_ws, size_t ws_size,
                              hipStream_t stream) {
    const float* x = (const float*)d_in[0];
    const float* W = (const float*)d_in[1];
    const int* maxit = (const int*)d_in[2];
    float* out = (float*)d_out;

    char* ws = (char*)d_ws;
    ull* slots = (ull*)ws;                                            // 16 KB
    float* partial_buf = (float*)(ws + (size_t)MAXE * 64);            // 128 KB
    if (ws_size < (size_t)(MAXE * 64 + 256 * BB * 4)) return;

    hipLaunchKernelGGL(hop_init, dim3(256), dim3(256), 0, stream,
                       x, W, slots, partial_buf);

    void* args[6];
    args[0] = (void*)&x; args[1] = (void*)&W; args[2] = (void*)&maxit;
    args[3] = (void*)&out; args[4] = (void*)&slots; args[5] = (void*)&partial_buf;
    (void)hipLaunchCooperativeKernel(hop_main, dim3(GG), dim3(NTH), args, 0u, stream);
}